// Round 1
// baseline (189.001 us; speedup 1.0000x reference)
//
#include <hip/hip_runtime.h>
#include <hip/hip_bf16.h>
#include <cstdint>

#define NN 100000
#define DEG 16
#define FF 256
#define UU 128

__device__ __forceinline__ unsigned short f2bf(float x) {
    uint32_t u = __builtin_bit_cast(uint32_t, x);
    uint32_t r = (u + 0x7fffu + ((u >> 16) & 1u)) >> 16;
    return (unsigned short)r;
}

// Kernel 1: h = ns @ W (fp32, W staged in LDS in two 64KB halves).
// Epilogue: a_src[n] = h[n] . ka[0:128], a_dst[n] = h[n] . ka[128:256],
// store h as bf16 for the gather phase.
// Block: 256 threads. Thread t: cols u0 = (t&31)*4, rows r0 = bid*32 + (t>>5)*4.
__global__ __launch_bounds__(256, 2) void k_gemm(
    const float* __restrict__ ns, const float* __restrict__ W,
    const float* __restrict__ ka, unsigned short* __restrict__ hb,
    float* __restrict__ a_src, float* __restrict__ a_dst)
{
    __shared__ float Wl[128 * UU];  // 64 KB: one K-half of W
    const int t = threadIdx.x;
    const int u0 = (t & 31) * 4;
    const int r0 = blockIdx.x * 32 + (t >> 5) * 4;

    float acc[4][4];
    #pragma unroll
    for (int i = 0; i < 4; ++i)
        #pragma unroll
        for (int j = 0; j < 4; ++j) acc[i][j] = 0.f;

    for (int half = 0; half < 2; ++half) {
        __syncthreads();  // all waves done reading previous half
        const float4* Wg = (const float4*)(W + half * 128 * UU);
        float4* Ws = (float4*)Wl;
        #pragma unroll
        for (int i = 0; i < 16; ++i) Ws[i * 256 + t] = Wg[i * 256 + t];
        __syncthreads();
        const float* na = ns + half * 128;
        for (int fc = 0; fc < 128; fc += 4) {
            float4 b0 = *(const float4*)&Wl[(fc + 0) * UU + u0];
            float4 b1 = *(const float4*)&Wl[(fc + 1) * UU + u0];
            float4 b2 = *(const float4*)&Wl[(fc + 2) * UU + u0];
            float4 b3 = *(const float4*)&Wl[(fc + 3) * UU + u0];
            #pragma unroll
            for (int i = 0; i < 4; ++i) {
                float4 a = *(const float4*)&na[(size_t)(r0 + i) * FF + fc];
                acc[i][0] = fmaf(a.x, b0.x, acc[i][0]);
                acc[i][0] = fmaf(a.y, b1.x, acc[i][0]);
                acc[i][0] = fmaf(a.z, b2.x, acc[i][0]);
                acc[i][0] = fmaf(a.w, b3.x, acc[i][0]);
                acc[i][1] = fmaf(a.x, b0.y, acc[i][1]);
                acc[i][1] = fmaf(a.y, b1.y, acc[i][1]);
                acc[i][1] = fmaf(a.z, b2.y, acc[i][1]);
                acc[i][1] = fmaf(a.w, b3.y, acc[i][1]);
                acc[i][2] = fmaf(a.x, b0.z, acc[i][2]);
                acc[i][2] = fmaf(a.y, b1.z, acc[i][2]);
                acc[i][2] = fmaf(a.z, b2.z, acc[i][2]);
                acc[i][2] = fmaf(a.w, b3.z, acc[i][2]);
                acc[i][3] = fmaf(a.x, b0.w, acc[i][3]);
                acc[i][3] = fmaf(a.y, b1.w, acc[i][3]);
                acc[i][3] = fmaf(a.z, b2.w, acc[i][3]);
                acc[i][3] = fmaf(a.w, b3.w, acc[i][3]);
            }
        }
    }

    // Epilogue: attention dot-products (reduce across the 32 lanes that share
    // each row group; xor masks < 32 stay within each 32-lane half-wave),
    // and bf16 h store.
    float4 kas = *(const float4*)&ka[u0];
    float4 kad = *(const float4*)&ka[UU + u0];
    #pragma unroll
    for (int i = 0; i < 4; ++i) {
        float ps = acc[i][0] * kas.x + acc[i][1] * kas.y +
                   acc[i][2] * kas.z + acc[i][3] * kas.w;
        float pd = acc[i][0] * kad.x + acc[i][1] * kad.y +
                   acc[i][2] * kad.z + acc[i][3] * kad.w;
        #pragma unroll
        for (int m = 1; m < 32; m <<= 1) {
            ps += __shfl_xor(ps, m, 64);
            pd += __shfl_xor(pd, m, 64);
        }
        if ((t & 31) == 0) {
            a_src[r0 + i] = ps;
            a_dst[r0 + i] = pd;
        }
        ushort4 hv;
        hv.x = f2bf(acc[i][0]);
        hv.y = f2bf(acc[i][1]);
        hv.z = f2bf(acc[i][2]);
        hv.w = f2bf(acc[i][3]);
        *(ushort4*)&hb[(size_t)(r0 + i) * UU + u0] = hv;
    }
}

// Kernel 2: one wave per node. src is sorted with exactly DEG=16 edges/node,
// so node n owns edges [16n, 16n+16). All four 16-lane groups compute the 16
// scores redundantly (same addresses -> broadcast coalesce), xor-reduce gives
// every lane the softmax denominator. Then each lane owns 2 of 128 output
// dims and accumulates the weighted bf16 h gather.
__global__ __launch_bounds__(256, 4) void k_agg(
    const int* __restrict__ edges, const float* __restrict__ ew,
    const float* __restrict__ a_src, const float* __restrict__ a_dst,
    const unsigned short* __restrict__ hb, float* __restrict__ out)
{
    const int lane = threadIdx.x & 63;
    const int n = blockIdx.x * 4 + (threadIdx.x >> 6);
    const int e = lane & 15;
    const int ei = n * DEG + e;

    const int dst = edges[2 * ei + 1];
    const float w = ew[ei];
    const float x0 = w * (a_src[n] + a_dst[dst]);
    float x = x0 > 0.f ? x0 : 0.2f * x0;        // leaky_relu, slope 0.2
    x = fminf(2.f, fmaxf(-2.f, x));             // clip
    const float s = expf(x);

    float ssum = s;
    ssum += __shfl_xor(ssum, 1, 64);
    ssum += __shfl_xor(ssum, 2, 64);
    ssum += __shfl_xor(ssum, 4, 64);
    ssum += __shfl_xor(ssum, 8, 64);
    const float norm = s / ssum;

    const int d0 = lane * 2;
    const unsigned short* hp = hb + d0;
    float acc0 = 0.f, acc1 = 0.f;
    #pragma unroll
    for (int j = 0; j < 16; ++j) {
        const float nj = __shfl(norm, j, 64);   // lane j holds edge j's norm
        const int dj = __shfl(dst, j, 64);
        const uint32_t hv = *(const uint32_t*)(hp + (size_t)dj * UU);
        const float h0 = __builtin_bit_cast(float, hv << 16);
        const float h1 = __builtin_bit_cast(float, hv & 0xffff0000u);
        acc0 = fmaf(nj, h0, acc0);
        acc1 = fmaf(nj, h1, acc1);
    }
    float2 o;
    o.x = acc0;
    o.y = acc1;
    *(float2*)&out[(size_t)n * UU + d0] = o;
}

extern "C" void kernel_launch(void* const* d_in, const int* in_sizes, int n_in,
                              void* d_out, int out_size, void* d_ws, size_t ws_size,
                              hipStream_t stream) {
    const float* ns    = (const float*)d_in[0];  // [1, N, 256] f32
    const int*   edges = (const int*)d_in[1];    // [1, E, 2] i32, src sorted
    const float* ew    = (const float*)d_in[2];  // [1, E] f32
    const float* W     = (const float*)d_in[3];  // [256, 128] f32
    const float* ka    = (const float*)d_in[4];  // [256, 1] f32
    float* out = (float*)d_out;                  // [N, 128] f32

    char* ws = (char*)d_ws;
    unsigned short* hb = (unsigned short*)ws;                  // N*128 bf16 = 25.6 MB
    float* a_src = (float*)(ws + (size_t)NN * UU * 2);         // N f32
    float* a_dst = a_src + NN;                                 // N f32

    k_gemm<<<NN / 32, 256, 0, stream>>>(ns, W, ka, hb, a_src, a_dst);  // 3125 blocks
    k_agg<<<NN / 4, 256, 0, stream>>>(edges, ew, a_src, a_dst, hb, out); // 25000 blocks
}

// Round 2
// 99.326 us; speedup vs baseline: 1.9028x; 1.9028x over previous
//
#include <hip/hip_runtime.h>
#include <hip/hip_bf16.h>
#include <cstdint>

#define NN 100000
#define DEG 16
#define FF 256
#define UU 128

typedef __attribute__((ext_vector_type(8))) short short8;
typedef __attribute__((ext_vector_type(4))) float f32x4;

__device__ __forceinline__ unsigned short f2bf(float x) {
    uint32_t u = __builtin_bit_cast(uint32_t, x);
    uint32_t r = (u + 0x7fffu + ((u >> 16) & 1u)) >> 16;
    return (unsigned short)r;
}
__device__ __forceinline__ float bf2f(unsigned short b) {
    return __builtin_bit_cast(float, (uint32_t)b << 16);
}

// Pre-kernel: W [256][128] f32 -> Wt [128][256] bf16 (transposed, 64 KB, L2-hot).
__global__ void k_convW(const float* __restrict__ W, unsigned short* __restrict__ Wt) {
    int i = blockIdx.x * 256 + threadIdx.x;  // 32768 elements
    int k = i >> 7, c = i & 127;
    Wt[c * 256 + k] = f2bf(W[i]);
}

// Main GEMM: h = ns @ W via bf16 MFMA. Block = 64 rows x 128 cols, 4 waves,
// wave w owns cols [w*32, w*32+32). B frags in registers; A tile staged
// fp32->bf16 into XOR-swizzled LDS. Epilogue: coalesced bf16 h store +
// fused a_src/a_dst attention dot products.
__global__ __launch_bounds__(256, 2) void k_gemm(
    const float* __restrict__ ns, const unsigned short* __restrict__ Wt,
    const float* __restrict__ ka, unsigned short* __restrict__ hb,
    float* __restrict__ a_src, float* __restrict__ a_dst)
{
    __shared__ char smem[64 * 512 + 1024];  // 32 KB A-tile (reused as Ht) + 1 KB ka
    float* ka_s = (float*)(smem + 64 * 512);
    const int t = threadIdx.x;
    const int lane = t & 63;
    const int w = t >> 6;
    const int row0 = blockIdx.x * 64;
    const int lrow = lane & 15;
    const int khalf = lane >> 4;

    if (t < 256) ka_s[t] = ka[t];

    // ---- B fragments (registers): bfrag[nt][ks], same (lane,reg)->k map as A ----
    short8 bfrag[2][8];
    {
        const int col0 = w * 32 + lrow;
        #pragma unroll
        for (int nt = 0; nt < 2; ++nt) {
            const unsigned short* wp = Wt + (size_t)(col0 + nt * 16) * 256 + khalf * 8;
            #pragma unroll
            for (int ks = 0; ks < 8; ++ks)
                bfrag[nt][ks] = *(const short8*)(wp + ks * 32);
        }
    }

    // ---- Stage A: 64x256 fp32 -> bf16 LDS, byte ^= (row&7)<<4 swizzle ----
    #pragma unroll
    for (int i = 0; i < 8; ++i) {
        int u = i * 256 + t;
        int row = u >> 5, c8 = u & 31;
        int gr = row0 + row;
        float4 x0, x1;
        if (gr < NN) {
            const float* gp = ns + (size_t)gr * FF + c8 * 8;
            x0 = *(const float4*)gp;
            x1 = *(const float4*)(gp + 4);
        } else {
            x0 = make_float4(0.f, 0.f, 0.f, 0.f);
            x1 = x0;
        }
        short8 v;
        v[0] = f2bf(x0.x); v[1] = f2bf(x0.y); v[2] = f2bf(x0.z); v[3] = f2bf(x0.w);
        v[4] = f2bf(x1.x); v[5] = f2bf(x1.y); v[6] = f2bf(x1.z); v[7] = f2bf(x1.w);
        int byte = (row * 512 + c8 * 16) ^ ((row & 7) << 4);
        *(short8*)(smem + byte) = v;
    }
    __syncthreads();

    // ---- K-loop: 8 ksteps x (4 ds_read_b128 + 8 MFMA) ----
    f32x4 acc[4][2];
    #pragma unroll
    for (int mt = 0; mt < 4; ++mt)
        #pragma unroll
        for (int nt = 0; nt < 2; ++nt)
            acc[mt][nt] = (f32x4){0.f, 0.f, 0.f, 0.f};

    #pragma unroll
    for (int ks = 0; ks < 8; ++ks) {
        short8 a[4];
        #pragma unroll
        for (int mt = 0; mt < 4; ++mt) {
            int row = mt * 16 + lrow;
            int byte = (row * 512 + ks * 64 + khalf * 16) ^ ((row & 7) << 4);
            a[mt] = *(const short8*)(smem + byte);
        }
        #pragma unroll
        for (int mt = 0; mt < 4; ++mt)
            #pragma unroll
            for (int nt = 0; nt < 2; ++nt)
                acc[mt][nt] = __builtin_amdgcn_mfma_f32_16x16x32_bf16(
                    a[mt], bfrag[nt][ks], acc[mt][nt], 0, 0, 0);
    }

    __syncthreads();  // A-tile reads done; reuse smem as Ht[64][136] ushort

    // ---- acc -> Ht (row stride 136 breaks bank aliasing) ----
    unsigned short* Hs = (unsigned short*)smem;
    {
        const int wcol = w * 32;
        #pragma unroll
        for (int mt = 0; mt < 4; ++mt)
            #pragma unroll
            for (int nt = 0; nt < 2; ++nt)
                #pragma unroll
                for (int r = 0; r < 4; ++r) {
                    int row = mt * 16 + khalf * 4 + r;
                    int col = wcol + nt * 16 + lrow;
                    Hs[row * 136 + col] = f2bf(acc[mt][nt][r]);
                }
    }
    __syncthreads();

    // ---- coalesced hb store + attention dots (4 threads per row) ----
    {
        int row = t >> 2, q = t & 3;
        int gr = row0 + row;
        float ps = 0.f, pd = 0.f;
        short8 hv[4];
        #pragma unroll
        for (int j = 0; j < 4; ++j) {
            hv[j] = *(const short8*)(Hs + row * 136 + q * 32 + j * 8);
            #pragma unroll
            for (int e = 0; e < 8; ++e) {
                float hf = bf2f((unsigned short)hv[j][e]);
                int c = q * 32 + j * 8 + e;
                ps = fmaf(hf, ka_s[c], ps);
                pd = fmaf(hf, ka_s[UU + c], pd);
            }
        }
        if (gr < NN) {
            short8* op = (short8*)(hb + (size_t)gr * UU + q * 32);
            op[0] = hv[0]; op[1] = hv[1]; op[2] = hv[2]; op[3] = hv[3];
        }
        ps += __shfl_xor(ps, 1, 64); ps += __shfl_xor(ps, 2, 64);
        pd += __shfl_xor(pd, 1, 64); pd += __shfl_xor(pd, 2, 64);
        if (q == 0 && gr < NN) { a_src[gr] = ps; a_dst[gr] = pd; }
    }
}

// Aggregation: one wave per node; 16 edges/node contiguous (src sorted).
__global__ __launch_bounds__(256, 4) void k_agg(
    const int* __restrict__ edges, const float* __restrict__ ew,
    const float* __restrict__ a_src, const float* __restrict__ a_dst,
    const unsigned short* __restrict__ hb, float* __restrict__ out)
{
    const int lane = threadIdx.x & 63;
    const int n = blockIdx.x * 4 + (threadIdx.x >> 6);
    const int e = lane & 15;
    const int ei = n * DEG + e;

    const int dst = edges[2 * ei + 1];
    const float w = ew[ei];
    const float x0 = w * (a_src[n] + a_dst[dst]);
    float x = x0 > 0.f ? x0 : 0.2f * x0;        // leaky_relu, slope 0.2
    x = fminf(2.f, fmaxf(-2.f, x));             // clip
    const float s = expf(x);

    float ssum = s;
    ssum += __shfl_xor(ssum, 1, 64);
    ssum += __shfl_xor(ssum, 2, 64);
    ssum += __shfl_xor(ssum, 4, 64);
    ssum += __shfl_xor(ssum, 8, 64);
    const float norm = s / ssum;

    const int d0 = lane * 2;
    const unsigned short* hp = hb + d0;
    float acc0 = 0.f, acc1 = 0.f;
    #pragma unroll
    for (int j = 0; j < 16; ++j) {
        const float nj = __shfl(norm, j, 64);
        const int dj = __shfl(dst, j, 64);
        const uint32_t hv = *(const uint32_t*)(hp + (size_t)dj * UU);
        const float h0 = __builtin_bit_cast(float, hv << 16);
        const float h1 = __builtin_bit_cast(float, hv & 0xffff0000u);
        acc0 = fmaf(nj, h0, acc0);
        acc1 = fmaf(nj, h1, acc1);
    }
    float2 o;
    o.x = acc0;
    o.y = acc1;
    *(float2*)&out[(size_t)n * UU + d0] = o;
}

extern "C" void kernel_launch(void* const* d_in, const int* in_sizes, int n_in,
                              void* d_out, int out_size, void* d_ws, size_t ws_size,
                              hipStream_t stream) {
    const float* ns    = (const float*)d_in[0];  // [1, N, 256] f32
    const int*   edges = (const int*)d_in[1];    // [1, E, 2] i32, src sorted
    const float* ew    = (const float*)d_in[2];  // [1, E] f32
    const float* W     = (const float*)d_in[3];  // [256, 128] f32
    const float* ka    = (const float*)d_in[4];  // [256, 1] f32
    float* out = (float*)d_out;                  // [N, 128] f32

    char* ws = (char*)d_ws;
    unsigned short* hb = (unsigned short*)ws;                    // N*128 bf16 = 25.6 MB
    float* a_src = (float*)(ws + (size_t)NN * UU * 2);           // N f32
    float* a_dst = a_src + NN;                                   // N f32
    unsigned short* Wt = (unsigned short*)(ws + (size_t)NN * UU * 2 + 2 * (size_t)NN * 4);  // 64 KB

    k_convW<<<FF * UU / 256, 256, 0, stream>>>(W, Wt);                    // 128 blocks
    k_gemm<<<(NN + 63) / 64, 256, 0, stream>>>(ns, Wt, ka, hb, a_src, a_dst);  // 1563 blocks
    k_agg<<<NN / 4, 256, 0, stream>>>(edges, ew, a_src, a_dst, hb, out);  // 25000 blocks
}